// Round 3
// baseline (641.532 us; speedup 1.0000x reference)
//
#include <hip/hip_runtime.h>
#include <cstdint>

#define P 7
#define PP 49
#define IMG 64
#define PIX 4096
#define PAD 3
#define XS 70     // padded tile dim
#define XSTR 71   // padded tile row stride (bank-conflict pad)

// ---------------------------------------------------------------------------
// Kernel A: one block per output channel c = l*64 + img (512 blocks).
// ONE pixel per thread per iteration (no multi-pixel unroll -> no spills).
// Per pixel: load the 7x7 window into registers in k-order while summing,
// then the sequential fmaf chain -- bit-identical op order to the verified
// rounds. __launch_bounds__(256,2) caps VGPRs at 128.
// ---------------------------------------------------------------------------
__global__ __launch_bounds__(256, 2) void stage_kernel(
    const float* __restrict__ x,    // [64][64][64]
    const float* __restrict__ W1,   // [49][8]
    const float* __restrict__ W2,   // [49][8]
    uint8_t* __restrict__ codes)    // [512][4096]
{
    __shared__ float xs[XS * XSTR];
    __shared__ float ms[XS * XSTR];
    __shared__ float w1[PP];
    __shared__ float w2[PP * 8];

    const int c   = blockIdx.x;
    const int l   = c >> 6;
    const int img = c & 63;
    const int tid = threadIdx.x;

    if (tid < PP) w1[tid] = W1[tid * 8 + l];
    for (int i = tid; i < PP * 8; i += 256) w2[i] = W2[i];

    // ---- load x, zero-padded by 3 on each side ----
    const float* xb = x + (size_t)img * PIX;
    #pragma unroll 1
    for (int idx = tid; idx < XS * XSTR; idx += 256) {
        int r  = idx / XSTR, cc = idx - r * XSTR;
        int xr = r - PAD,    xc = cc - PAD;
        float v = 0.f;
        if (xr >= 0 && xr < IMG && xc >= 0 && xc < IMG)
            v = xb[xr * IMG + xc];
        xs[idx] = v;
    }
    __syncthreads();

    // ---- stage 1: maps1 channel (l,img) over padded 70x70 ----
    #pragma unroll 1
    for (int idx = tid; idx < XS * XS; idx += 256) {
        int r  = idx / XS, cc = idx - r * XS;
        int mr = r - PAD,  mc = cc - PAD;
        float val = 0.f;
        if (mr >= 0 && mr < IMG && mc >= 0 && mc < IMG) {
            const float* base = &xs[mr * XSTR + mc];
            float p[PP];
            float s = 0.f;
            #pragma unroll
            for (int i = 0; i < P; ++i) {
                #pragma unroll
                for (int j = 0; j < P; ++j) {
                    float v = base[i * XSTR + j];
                    p[i * P + j] = v;
                    s += v;
                }
            }
            float mu  = s / 49.0f;
            float acc = 0.f;
            #pragma unroll
            for (int k = 0; k < PP; ++k)
                acc = fmaf(w1[k], p[k] - mu, acc);
            val = acc;
        }
        ms[r * XSTR + cc] = val;
    }
    __syncthreads();

    // ---- stage 2 + code bits: one pixel per thread, byte store ----
    uint8_t* cg = codes + (size_t)c * PIX;
    #pragma unroll 1
    for (int p0 = tid; p0 < PIX; p0 += 256) {
        int pr = p0 >> 6, pc = p0 & 63;
        const float* mbase = &ms[pr * XSTR + pc];
        float q[PP];
        float s = 0.f;
        #pragma unroll
        for (int i = 0; i < P; ++i) {
            #pragma unroll
            for (int j = 0; j < P; ++j) {
                float v = mbase[i * XSTR + j];
                q[i * P + j] = v;
                s += v;
            }
        }
        float mu = s / 49.0f;
        float acc0 = 0.f, acc1 = 0.f, acc2 = 0.f, acc3 = 0.f;
        float acc4 = 0.f, acc5 = 0.f, acc6 = 0.f, acc7 = 0.f;
        #pragma unroll
        for (int k = 0; k < PP; ++k) {
            float t = q[k] - mu;
            acc0 = fmaf(w2[k * 8 + 0], t, acc0);
            acc1 = fmaf(w2[k * 8 + 1], t, acc1);
            acc2 = fmaf(w2[k * 8 + 2], t, acc2);
            acc3 = fmaf(w2[k * 8 + 3], t, acc3);
            acc4 = fmaf(w2[k * 8 + 4], t, acc4);
            acc5 = fmaf(w2[k * 8 + 5], t, acc5);
            acc6 = fmaf(w2[k * 8 + 6], t, acc6);
            acc7 = fmaf(w2[k * 8 + 7], t, acc7);
        }
        uint32_t code = 0;
        code |= (acc0 > 0.f) ? 128u : 0u;
        code |= (acc1 > 0.f) ?  64u : 0u;
        code |= (acc2 > 0.f) ?  32u : 0u;
        code |= (acc3 > 0.f) ?  16u : 0u;
        code |= (acc4 > 0.f) ?   8u : 0u;
        code |= (acc5 > 0.f) ?   4u : 0u;
        code |= (acc6 > 0.f) ?   2u : 0u;
        code |= (acc7 > 0.f) ?   1u : 0u;
        cg[p0] = (uint8_t)code;
    }
}

// ---------------------------------------------------------------------------
// Kernel B: histogram + entropy (unchanged -- not the bottleneck)
// ---------------------------------------------------------------------------
#define CPB 32

__global__ __launch_bounds__(256) void hist_kernel(
    const uint8_t* __restrict__ codes,  // [512][4096]
    float* __restrict__ out)            // [49*256][512]
{
    __shared__ uint32_t hist[256 * 33];

    const int bid   = blockIdx.x;       // 0..783
    const int cgrp  = bid & 15;
    const int nb    = bid >> 4;         // 0..48
    const int bi    = nb / 7, bj = nb - bi * 7;
    const int tid   = threadIdx.x;
    const int cbase = cgrp * CPB;

    for (int i = tid; i < 256 * 33; i += 256) hist[i] = 0;
    __syncthreads();

    const int cl  = tid >> 3;           // 0..31
    const int sub = tid & 7;            // 0..7
    const uint8_t* cp = codes + (size_t)(cbase + cl) * PIX;
    #pragma unroll
    for (int rr = 0; rr < 2; ++rr) {
        int row = bi * 8 + (sub * 2 + rr);
        const uint8_t* rp = cp + row * 64 + bj * 8;
        uint64_t v0 = *(const uint64_t*)(rp);
        uint64_t v1 = *(const uint64_t*)(rp + 8);
        #pragma unroll
        for (int t = 0; t < 8; ++t)
            atomicAdd(&hist[(uint32_t)((v0 >> (8 * t)) & 255u) * 33 + cl], 1u);
        #pragma unroll
        for (int t = 0; t < 8; ++t)
            atomicAdd(&hist[(uint32_t)((v1 >> (8 * t)) & 255u) * 33 + cl], 1u);
    }
    __syncthreads();

    const int lane_c = tid & 31;
    const int bin0   = tid >> 5;        // 0..7
    for (int i = 0; i < 32; ++i) {
        int bin = i * 8 + bin0;
        uint32_t cnt = hist[bin * 33 + lane_c];
        float ent = 0.f;
        if (cnt > 0) {
            float pz = (float)cnt * (1.0f / 256.0f);
            ent = -pz * log2f(pz);
        }
        out[((size_t)(nb * 256 + bin)) * 512 + cbase + lane_c] = ent;
    }
}

extern "C" void kernel_launch(void* const* d_in, const int* in_sizes, int n_in,
                              void* d_out, int out_size, void* d_ws, size_t ws_size,
                              hipStream_t stream) {
    const float* x  = (const float*)d_in[0];
    const float* W1 = (const float*)d_in[1];
    const float* W2 = (const float*)d_in[2];
    float* out = (float*)d_out;
    uint8_t* codes = (uint8_t*)d_ws;   // 512*4096 = 2 MB

    stage_kernel<<<512, 256, 0, stream>>>(x, W1, W2, codes);
    hist_kernel<<<784, 256, 0, stream>>>(codes, out);
}

// Round 4
// 170.477 us; speedup vs baseline: 3.7631x; 3.7631x over previous
//
#include <hip/hip_runtime.h>
#include <cstdint>

#define P 7
#define PP 49
#define IMG 64
#define PIX 4096
#define PAD 3
#define XS 70     // padded tile dim
#define XSTR 71   // padded tile row stride (bank-conflict pad)

// ---------------------------------------------------------------------------
// Kernel A: one block per output channel c = l*64 + img (512 blocks).
// No per-thread arrays (promote-alloca sent them to scratch in r1-r3).
// Per pixel: pass 1 sums the 7x7 window via a VOLATILE LDS pointer (cannot
// be CSE'd -> nothing stays live), sched_barrier, pass 2 re-reads the window
// normally and runs the fmaf(w, v-mu) chain in k-order -- bit-identical op
// order to the verified rounds. Weights are read directly from global with
// uniform addresses -> scalar loads on the scalar pipe, keeping the DS pipe
// free for the 98 data reads/pixel.
// ---------------------------------------------------------------------------
__global__ __launch_bounds__(256) void stage_kernel(
    const float* __restrict__ x,    // [64][64][64]
    const float* __restrict__ W1,   // [49][8]
    const float* __restrict__ W2,   // [49][8]
    uint8_t* __restrict__ codes)    // [512][4096]
{
    __shared__ float xs[XS * XSTR];
    __shared__ float ms[XS * XSTR];

    const int c   = blockIdx.x;
    const int l   = c >> 6;
    const int img = c & 63;
    const int tid = threadIdx.x;

    // ---- load x, zero-padded by 3 on each side ----
    const float* xb = x + (size_t)img * PIX;
    #pragma unroll 1
    for (int idx = tid; idx < XS * XSTR; idx += 256) {
        int r  = idx / XSTR, cc = idx - r * XSTR;
        int xr = r - PAD,    xc = cc - PAD;
        float v = 0.f;
        if (xr >= 0 && xr < IMG && xc >= 0 && xc < IMG)
            v = xb[xr * IMG + xc];
        xs[idx] = v;
    }
    __syncthreads();

    volatile const float* vxs = xs;
    volatile const float* vms = ms;

    // ---- stage 1: maps1 channel (l,img) over padded 70x70 ----
    #pragma unroll 1
    for (int idx = tid; idx < XS * XS; idx += 256) {
        int r  = idx / XS, cc = idx - r * XS;
        int mr = r - PAD,  mc = cc - PAD;
        float val = 0.f;
        if (mr >= 0 && mr < IMG && mc >= 0 && mc < IMG) {
            const int b0 = mr * XSTR + mc;
            float s = 0.f;
            #pragma unroll
            for (int i = 0; i < P; ++i)
                #pragma unroll
                for (int j = 0; j < P; ++j)
                    s += vxs[b0 + i * XSTR + j];
            float mu = s / 49.0f;
            __builtin_amdgcn_sched_barrier(0);
            float acc = 0.f;
            #pragma unroll
            for (int i = 0; i < P; ++i)
                #pragma unroll
                for (int j = 0; j < P; ++j)
                    acc = fmaf(W1[(i * P + j) * 8 + l],
                               xs[b0 + i * XSTR + j] - mu, acc);
            val = acc;
        }
        ms[r * XSTR + cc] = val;
    }
    __syncthreads();

    // ---- stage 2 + code bits: one pixel per thread, byte store ----
    uint8_t* cg = codes + (size_t)c * PIX;
    #pragma unroll 1
    for (int p0 = tid; p0 < PIX; p0 += 256) {
        int pr = p0 >> 6, pc = p0 & 63;
        const int b0 = pr * XSTR + pc;
        float s = 0.f;
        #pragma unroll
        for (int i = 0; i < P; ++i)
            #pragma unroll
            for (int j = 0; j < P; ++j)
                s += vms[b0 + i * XSTR + j];
        float mu = s / 49.0f;
        __builtin_amdgcn_sched_barrier(0);
        float acc0 = 0.f, acc1 = 0.f, acc2 = 0.f, acc3 = 0.f;
        float acc4 = 0.f, acc5 = 0.f, acc6 = 0.f, acc7 = 0.f;
        #pragma unroll
        for (int i = 0; i < P; ++i) {
            #pragma unroll
            for (int j = 0; j < P; ++j) {
                int k = i * P + j;
                float t = ms[b0 + i * XSTR + j] - mu;
                acc0 = fmaf(W2[k * 8 + 0], t, acc0);
                acc1 = fmaf(W2[k * 8 + 1], t, acc1);
                acc2 = fmaf(W2[k * 8 + 2], t, acc2);
                acc3 = fmaf(W2[k * 8 + 3], t, acc3);
                acc4 = fmaf(W2[k * 8 + 4], t, acc4);
                acc5 = fmaf(W2[k * 8 + 5], t, acc5);
                acc6 = fmaf(W2[k * 8 + 6], t, acc6);
                acc7 = fmaf(W2[k * 8 + 7], t, acc7);
            }
        }
        uint32_t code = 0;
        code |= (acc0 > 0.f) ? 128u : 0u;
        code |= (acc1 > 0.f) ?  64u : 0u;
        code |= (acc2 > 0.f) ?  32u : 0u;
        code |= (acc3 > 0.f) ?  16u : 0u;
        code |= (acc4 > 0.f) ?   8u : 0u;
        code |= (acc5 > 0.f) ?   4u : 0u;
        code |= (acc6 > 0.f) ?   2u : 0u;
        code |= (acc7 > 0.f) ?   1u : 0u;
        cg[p0] = (uint8_t)code;
    }
}

// ---------------------------------------------------------------------------
// Kernel B: histogram + entropy (unchanged -- ~3 us, not the bottleneck)
// ---------------------------------------------------------------------------
#define CPB 32

__global__ __launch_bounds__(256) void hist_kernel(
    const uint8_t* __restrict__ codes,  // [512][4096]
    float* __restrict__ out)            // [49*256][512]
{
    __shared__ uint32_t hist[256 * 33];

    const int bid   = blockIdx.x;       // 0..783
    const int cgrp  = bid & 15;
    const int nb    = bid >> 4;         // 0..48
    const int bi    = nb / 7, bj = nb - bi * 7;
    const int tid   = threadIdx.x;
    const int cbase = cgrp * CPB;

    for (int i = tid; i < 256 * 33; i += 256) hist[i] = 0;
    __syncthreads();

    const int cl  = tid >> 3;           // 0..31
    const int sub = tid & 7;            // 0..7
    const uint8_t* cp = codes + (size_t)(cbase + cl) * PIX;
    #pragma unroll
    for (int rr = 0; rr < 2; ++rr) {
        int row = bi * 8 + (sub * 2 + rr);
        const uint8_t* rp = cp + row * 64 + bj * 8;
        uint64_t v0 = *(const uint64_t*)(rp);
        uint64_t v1 = *(const uint64_t*)(rp + 8);
        #pragma unroll
        for (int t = 0; t < 8; ++t)
            atomicAdd(&hist[(uint32_t)((v0 >> (8 * t)) & 255u) * 33 + cl], 1u);
        #pragma unroll
        for (int t = 0; t < 8; ++t)
            atomicAdd(&hist[(uint32_t)((v1 >> (8 * t)) & 255u) * 33 + cl], 1u);
    }
    __syncthreads();

    const int lane_c = tid & 31;
    const int bin0   = tid >> 5;        // 0..7
    for (int i = 0; i < 32; ++i) {
        int bin = i * 8 + bin0;
        uint32_t cnt = hist[bin * 33 + lane_c];
        float ent = 0.f;
        if (cnt > 0) {
            float pz = (float)cnt * (1.0f / 256.0f);
            ent = -pz * log2f(pz);
        }
        out[((size_t)(nb * 256 + bin)) * 512 + cbase + lane_c] = ent;
    }
}

extern "C" void kernel_launch(void* const* d_in, const int* in_sizes, int n_in,
                              void* d_out, int out_size, void* d_ws, size_t ws_size,
                              hipStream_t stream) {
    const float* x  = (const float*)d_in[0];
    const float* W1 = (const float*)d_in[1];
    const float* W2 = (const float*)d_in[2];
    float* out = (float*)d_out;
    uint8_t* codes = (uint8_t*)d_ws;   // 512*4096 = 2 MB

    stage_kernel<<<512, 256, 0, stream>>>(x, W1, W2, codes);
    hist_kernel<<<784, 256, 0, stream>>>(codes, out);
}